// Round 14
// baseline (7553.108 us; speedup 1.0000x reference)
//
#include <hip/hip_runtime.h>
#include <hip/hip_bf16.h>
#include <stdint.h>

typedef unsigned int u32;
typedef unsigned short u16;
typedef short bf16x8 __attribute__((ext_vector_type(8)));
typedef float f32x4 __attribute__((ext_vector_type(4)));
typedef u32 u32x4 __attribute__((ext_vector_type(4)));

#define T_STEPS 1024
#define BATCH   64
#define DIM     1024
#define NGRP    8        // 8 independent groups, 8 batch rows each
#define GWG     32       // WGs per group; each owns 32 hidden cols
#define NTHR    512      // 8 waves
#define SENT    0xFFFFFFFFu   // bf16 NaN|NaN — unreachable (|H|<=1)

__device__ __forceinline__ u16 f2bf(float f) {
  u32 u = __float_as_uint(f);
  return (u16)((u + 0x7FFFu + ((u >> 16) & 1u)) >> 16);
}
__device__ __forceinline__ float sigm(float x) { return 1.0f / (1.0f + __expf(-x)); }
__device__ __forceinline__ float tanh_f(float x) {
  x = fminf(8.0f, fmaxf(-8.0f, x));
  float e = __expf(2.0f * x);
  return (e - 1.0f) / (e + 1.0f);
}

// pack: idx = ((((wid*8+wv)*2+cg)*3+n)*4+ks)*64+lane, 8 u16 each (r8/r11/r13-verified)
// k0 = wv*128 + ks*32 + (lane>>4)*8 ; col = wid*32 + cg*16 + (lane&15)
__global__ void gru_pack3(const float* __restrict__ Wz, const float* __restrict__ Wr,
                          const float* __restrict__ Wh, u16* __restrict__ wp) {
  int idx = blockIdx.x * 256 + threadIdx.x;
  if (idx >= GWG * 8 * 2 * 3 * 4 * 64) return;
  int lane = idx & 63; int r = idx >> 6;
  int ks = r & 3; r >>= 2;
  int n = r % 3; r /= 3;
  int cg = r & 1; r >>= 1;
  int wv = r & 7; int wid = r >> 3;
  int k0 = wv * 128 + ks * 32 + (lane >> 4) * 8;
  int col = wid * 32 + cg * 16 + (lane & 15);
  const float* W = (n == 0) ? Wz : (n == 1) ? Wr : Wh;
  u16* dst = wp + (size_t)idx * 8;
#pragma unroll
  for (int j = 0; j < 8; ++j) dst[j] = f2bf(W[(size_t)(k0 + j) * DIM + col]);
}

#define WAIT0 asm volatile("s_waitcnt vmcnt(0)" ::: "memory"); __builtin_amdgcn_sched_barrier(0)
#define MFMA_(A, B, C) __builtin_amdgcn_mfma_f32_16x16x32_bf16(__builtin_bit_cast(bf16x8, A), B, C, 0, 0, 0)
#define PK2(a, b) ((((u32)f2bf(b)) << 16) | (u32)f2bf(a))

// ---------------- persistent scan: 8 groups x 32 WGs, pure dataflow ----------------
// H(t) -> fresh sentinel-armed slot (no reuse). Producers fire sc0 sc1 stores and move
// on (no drain, no flag). Consumers load-verify-retry BEFORE MFMA. Nothing can hang:
// no flags, no election, no cross-WG waits except on data that is unconditionally
// produced. Grid=256 at 1 WG/CU -> co-resident.
__launch_bounds__(NTHR, 2)
__global__ void gru_scan(const float* __restrict__ inputs,
                         const float* __restrict__ bz, const float* __restrict__ br,
                         const float* __restrict__ bh,
                         const u16* __restrict__ wpackH, const u16* __restrict__ wpackX,
                         u32* hhist, float* __restrict__ out) {
  __shared__ float part[8][2][4][64][6];   // 96KB, lane-cell layout (r13)

  const int tid = threadIdx.x;
  const int g   = blockIdx.x >> 5;
  const int wid = blockIdx.x & 31;
  const int wv = tid >> 6;
  const int lane = tid & 63;

  // Wh + Wx register-resident: 2 x 96 VGPR (asm-laundered; r13-proven)
  bf16x8 bregH[2][3][4], bregX[2][3][4];
  {
    const u16* wph = wpackH + (size_t)(wid * 8 + wv) * (2 * 3 * 4 * 512);
    const u16* wpx = wpackX + (size_t)(wid * 8 + wv) * (2 * 3 * 4 * 512);
#pragma unroll
    for (int cg = 0; cg < 2; ++cg)
#pragma unroll
      for (int n = 0; n < 3; ++n)
#pragma unroll
        for (int ks = 0; ks < 4; ++ks) {
          const int off = (((cg * 3 + n) * 4 + ks) * 512) + lane * 8;
          bregH[cg][n][ks] = *(const bf16x8*)(wph + off);
          asm volatile("" : "+v"(bregH[cg][n][ks]));
          bregX[cg][n][ks] = *(const bf16x8*)(wpx + off);
          asm volatile("" : "+v"(bregX[cg][n][ks]));
        }
  }

  // gate-stage ownership (tid<128): (row, colpair)
  const int grow = tid >> 4;                     // 0..7 (valid when tid<128)
  const int cp = tid & 15;
  const int cgg = cp >> 3;
  const int c16 = 2 * (cp & 7);
  const int col0 = wid * 32 + cgg * 16 + c16;
  const float b_z0 = bz[col0], b_z1 = bz[col0 + 1];
  const float b_r0 = br[col0], b_r1 = br[col0 + 1];
  const float b_h0 = bh[col0], b_h1 = bh[col0 + 1];
  const int cell0 = (grow >> 2) * 16 + c16;
  const int wrd = grow & 3;
  float hp0 = 0.f, hp1 = 0.f;

  f32x4 xc[2][3];
  // x-acc for step ts: A = this group's 8 batch rows (lanes 8-15 of each 16 zeroed),
  // f32 inputs converted in-flight, Wx from REGISTERS. Runs off the critical path.
#define COMPX(ts) { \
  u32x4 xa0, xa1, xa2, xa3; \
  const float* xb_ = inputs + (size_t)(ts) * (BATCH * DIM) \
                   + (size_t)(8 * g + (lane & 7)) * DIM + wv * 128 + (lane >> 4) * 8; \
  { f32x4 lo, hi; \
    lo = *(const f32x4*)(xb_ + 0);  hi = *(const f32x4*)(xb_ + 4); \
    xa0[0]=PK2(lo[0],lo[1]); xa0[1]=PK2(lo[2],lo[3]); xa0[2]=PK2(hi[0],hi[1]); xa0[3]=PK2(hi[2],hi[3]); \
    lo = *(const f32x4*)(xb_ + 32); hi = *(const f32x4*)(xb_ + 36); \
    xa1[0]=PK2(lo[0],lo[1]); xa1[1]=PK2(lo[2],lo[3]); xa1[2]=PK2(hi[0],hi[1]); xa1[3]=PK2(hi[2],hi[3]); \
    lo = *(const f32x4*)(xb_ + 64); hi = *(const f32x4*)(xb_ + 68); \
    xa2[0]=PK2(lo[0],lo[1]); xa2[1]=PK2(lo[2],lo[3]); xa2[2]=PK2(hi[0],hi[1]); xa2[3]=PK2(hi[2],hi[3]); \
    lo = *(const f32x4*)(xb_ + 96); hi = *(const f32x4*)(xb_ + 100); \
    xa3[0]=PK2(lo[0],lo[1]); xa3[1]=PK2(lo[2],lo[3]); xa3[2]=PK2(hi[0],hi[1]); xa3[3]=PK2(hi[2],hi[3]); } \
  if ((lane & 15) >= 8) { xa0 = (u32x4){0,0,0,0}; xa1 = (u32x4){0,0,0,0}; \
                          xa2 = (u32x4){0,0,0,0}; xa3 = (u32x4){0,0,0,0}; } \
  _Pragma("unroll") for (int cg_ = 0; cg_ < 2; ++cg_) \
  _Pragma("unroll") for (int n_ = 0; n_ < 3; ++n_) { \
    f32x4 a_ = (f32x4){0.f, 0.f, 0.f, 0.f}; \
    a_ = MFMA_(xa0, bregX[cg_][n_][0], a_); \
    a_ = MFMA_(xa1, bregX[cg_][n_][1], a_); \
    a_ = MFMA_(xa2, bregX[cg_][n_][2], a_); \
    a_ = MFMA_(xa3, bregX[cg_][n_][3], a_); \
    xc[cg_][n_] = a_; } }

  COMPX(0);

#pragma unroll 1
  for (int t = 0; t < T_STEPS; ++t) {
    // z/r: h-MFMA accumulates directly into the x-partial (C-in = xc)
    f32x4 vz[2], vr[2], vhh[2];
#pragma unroll
    for (int cg = 0; cg < 2; ++cg) {
      vz[cg] = xc[cg][0]; vr[cg] = xc[cg][1]; vhh[cg] = (f32x4){0.f, 0.f, 0.f, 0.f};
    }

    if (t > 0) {
      // ---- load H(t-1) from its fresh slot; the DATA is the flag (sentinel-verify) ----
      const u32* hb = hhist + ((size_t)(t - 1) * NGRP + g) * 4096
                    + (size_t)(lane & 7) * 512 + wv * 64 + (lane >> 4) * 4;
      u32x4 ha0, ha1, ha2, ha3;
      for (;;) {
        asm volatile("global_load_dwordx4 %0, %1, off sc0 sc1" : "=v"(ha0) : "v"(hb));
        asm volatile("global_load_dwordx4 %0, %1, off offset:64 sc0 sc1" : "=v"(ha1) : "v"(hb));
        asm volatile("global_load_dwordx4 %0, %1, off offset:128 sc0 sc1" : "=v"(ha2) : "v"(hb));
        asm volatile("global_load_dwordx4 %0, %1, off offset:192 sc0 sc1" : "=v"(ha3) : "v"(hb));
        WAIT0;
        u32 bad = (u32)(ha0[0] == SENT) | (u32)(ha0[1] == SENT)
                | (u32)(ha0[2] == SENT) | (u32)(ha0[3] == SENT)
                | (u32)(ha1[0] == SENT) | (u32)(ha1[1] == SENT)
                | (u32)(ha1[2] == SENT) | (u32)(ha1[3] == SENT)
                | (u32)(ha2[0] == SENT) | (u32)(ha2[1] == SENT)
                | (u32)(ha2[2] == SENT) | (u32)(ha2[3] == SENT)
                | (u32)(ha3[0] == SENT) | (u32)(ha3[1] == SENT)
                | (u32)(ha3[2] == SENT) | (u32)(ha3[3] == SENT);
        if (__all((int)(bad == 0))) break;
        __builtin_amdgcn_s_sleep(1);
      }
      asm volatile("" ::: "memory");
      if ((lane & 15) >= 8) { ha0 = (u32x4){0,0,0,0}; ha1 = (u32x4){0,0,0,0};
                              ha2 = (u32x4){0,0,0,0}; ha3 = (u32x4){0,0,0,0}; }
#pragma unroll
      for (int cg = 0; cg < 2; ++cg) {
        vz[cg] = MFMA_(ha0, bregH[cg][0][0], vz[cg]);
        vz[cg] = MFMA_(ha1, bregH[cg][0][1], vz[cg]);
        vz[cg] = MFMA_(ha2, bregH[cg][0][2], vz[cg]);
        vz[cg] = MFMA_(ha3, bregH[cg][0][3], vz[cg]);
        vr[cg] = MFMA_(ha0, bregH[cg][1][0], vr[cg]);
        vr[cg] = MFMA_(ha1, bregH[cg][1][1], vr[cg]);
        vr[cg] = MFMA_(ha2, bregH[cg][1][2], vr[cg]);
        vr[cg] = MFMA_(ha3, bregH[cg][1][3], vr[cg]);
        vhh[cg] = MFMA_(ha0, bregH[cg][2][0], vhh[cg]);
        vhh[cg] = MFMA_(ha1, bregH[cg][2][1], vhh[cg]);
        vhh[cg] = MFMA_(ha2, bregH[cg][2][2], vhh[cg]);
        vhh[cg] = MFMA_(ha3, bregH[cg][2][3], vhh[cg]);
      }
    }

    // ---- partials: z (x+h), r (x+h), xh, hh — lane-cell layout ----
#pragma unroll
    for (int cg = 0; cg < 2; ++cg) {
      *(float2*)&part[wv][cg][0][lane][0] = make_float2(vz[cg][0], vz[cg][1]);
      *(float2*)&part[wv][cg][0][lane][2] = make_float2(vz[cg][2], vz[cg][3]);
      *(float2*)&part[wv][cg][1][lane][0] = make_float2(vr[cg][0], vr[cg][1]);
      *(float2*)&part[wv][cg][1][lane][2] = make_float2(vr[cg][2], vr[cg][3]);
      *(float2*)&part[wv][cg][2][lane][0] = make_float2(xc[cg][2][0], xc[cg][2][1]);
      *(float2*)&part[wv][cg][2][lane][2] = make_float2(xc[cg][2][2], xc[cg][2][3]);
      *(float2*)&part[wv][cg][3][lane][0] = make_float2(vhh[cg][0], vhh[cg][1]);
      *(float2*)&part[wv][cg][3][lane][2] = make_float2(vhh[cg][2], vhh[cg][3]);
    }
    __syncthreads();

    float hn0 = 0.f, hn1 = 0.f;
    if (tid < 128) {
      float sz0 = 0, sz1 = 0, sr0 = 0, sr1 = 0, sx0 = 0, sx1 = 0, sh0 = 0, sh1 = 0;
#pragma unroll
      for (int w = 0; w < 8; ++w) {
        sz0 += part[w][cgg][0][cell0][wrd];     sz1 += part[w][cgg][0][cell0 + 1][wrd];
        sr0 += part[w][cgg][1][cell0][wrd];     sr1 += part[w][cgg][1][cell0 + 1][wrd];
        sx0 += part[w][cgg][2][cell0][wrd];     sx1 += part[w][cgg][2][cell0 + 1][wrd];
        sh0 += part[w][cgg][3][cell0][wrd];     sh1 += part[w][cgg][3][cell0 + 1][wrd];
      }
      float z0 = sigm(sz0 + b_z0), z1 = sigm(sz1 + b_z1);
      float r0 = sigm(sr0 + b_r0), r1 = sigm(sr1 + b_r1);
      float th0 = tanh_f(sx0 + b_h0 + r0 * sh0);
      float th1 = tanh_f(sx1 + b_h1 + r1 * sh1);
      hn0 = z0 * hp0 + (1.f - z0) * th0;
      hn1 = z1 * hp1 + (1.f - z1) * th1;
      hp0 = hn0; hp1 = hn1;
      // fire-and-forget publish: data IS the flag (no drain, no barrier-tail)
      u32 pk = ((u32)f2bf(hn1) << 16) | f2bf(hn0);
      u32* hpw = hhist + ((size_t)t * NGRP + g) * 4096 + (size_t)grow * 512 + wid * 16 + cp;
      asm volatile("global_store_dword %0, %1, off sc0 sc1" :: "v"(hpw), "v"(pk) : "memory");
    }
    __syncthreads();   // LDS WAR only

    // out stores + next x-acc AFTER publish (off the critical chain)
    if (tid < 128) {
      float* op = out + (size_t)t * (BATCH * DIM) + (size_t)(8 * g + grow) * DIM + col0;
      *(float2*)op = make_float2(hn0, hn1);
      if (t == T_STEPS - 1) {
        float* fo = out + (size_t)T_STEPS * (BATCH * DIM) + (size_t)(8 * g + grow) * DIM + col0;
        *(float2*)fo = make_float2(hn0, hn1);
      }
    }
    if (t + 1 < T_STEPS) COMPX(t + 1);
  }
#undef COMPX
}

extern "C" void kernel_launch(void* const* d_in, const int* in_sizes, int n_in,
                              void* d_out, int out_size, void* d_ws, size_t ws_size,
                              hipStream_t stream) {
  const float* inputs = (const float*)d_in[0];
  const float* Wxz = (const float*)d_in[1];
  const float* Whz = (const float*)d_in[2];
  const float* bz  = (const float*)d_in[3];
  const float* Wxr = (const float*)d_in[4];
  const float* Whr = (const float*)d_in[5];
  const float* br  = (const float*)d_in[6];
  const float* Wxh = (const float*)d_in[7];
  const float* Whh = (const float*)d_in[8];
  const float* bh  = (const float*)d_in[9];
  float* out = (float*)d_out;

  // ws: hhist@0 (128MB: 1024 steps x 8 groups x 16KB, sentinel-armed, no reuse)
  //     | wpackH@128MB (6.29MB) | wpackX (6.29MB)   => ~146.8MB (within proven budget)
  char* ws = (char*)d_ws;
  u32* hhist  = (u32*)ws;
  size_t hhist_bytes = (size_t)T_STEPS * NGRP * 4096 * 4;   // 134217728
  u16* wpackH = (u16*)(ws + hhist_bytes);
  u16* wpackX = (u16*)(ws + hhist_bytes + 6291456);
  size_t need = hhist_bytes + 2 * 6291456;
  if (ws_size < need) return;  // fail visibly (output stays poisoned)

  // re-arm sentinels EVERY call (graph replays don't re-poison ws) — r8-proven pattern
  hipMemsetAsync(hhist, 0xFF, hhist_bytes, stream);

  const int pk = GWG * 8 * 2 * 3 * 4 * 64;
  hipLaunchKernelGGL(gru_pack3, dim3((pk + 255) / 256), dim3(256), 0, stream,
                     Whz, Whr, Whh, wpackH);
  hipLaunchKernelGGL(gru_pack3, dim3((pk + 255) / 256), dim3(256), 0, stream,
                     Wxz, Wxr, Wxh, wpackX);
  hipLaunchKernelGGL(gru_scan, dim3(NGRP * GWG), dim3(NTHR), 0, stream,
                     inputs, bz, br, bh, wpackH, wpackX, hhist, out);
}